// Round 13
// baseline (216.925 us; speedup 1.0000x reference)
//
#include <hip/hip_runtime.h>
#include <stdint.h>
#include <math.h>

#define NPTS   16384
#define NBATCH 64
#define NITER  256
#define NSAMP  6
#define PPT    16         // points per thread
#define NCHUNK 4          // point chunks (256 thr * PPT pts each)
#define ISPLIT 8          // iteration splits
#define IPB    (NITER / ISPLIT)   // iterations per block = 32

// ---------------- Threefry-2x32 (exact JAX semantics) ----------------
__device__ __forceinline__ uint32_t rotl32(uint32_t v, uint32_t r) {
  return (v << r) | (v >> (32u - r));
}
__device__ __forceinline__ void tf_round(uint32_t& x0, uint32_t& x1, uint32_t r) {
  x0 += x1; x1 = rotl32(x1, r); x1 ^= x0;
}
__device__ void threefry2x32(uint32_t k0, uint32_t k1, uint32_t x0, uint32_t x1,
                             uint32_t& o0, uint32_t& o1) {
  uint32_t ks2 = k0 ^ k1 ^ 0x1BD11BDAu;
  x0 += k0; x1 += k1;
  tf_round(x0,x1,13); tf_round(x0,x1,15); tf_round(x0,x1,26); tf_round(x0,x1,6);
  x0 += k1; x1 += ks2 + 1u;
  tf_round(x0,x1,17); tf_round(x0,x1,29); tf_round(x0,x1,16); tf_round(x0,x1,24);
  x0 += ks2; x1 += k0 + 2u;
  tf_round(x0,x1,13); tf_round(x0,x1,15); tf_round(x0,x1,26); tf_round(x0,x1,6);
  x0 += k0; x1 += k1 + 3u;
  tf_round(x0,x1,17); tf_round(x0,x1,29); tf_round(x0,x1,16); tf_round(x0,x1,24);
  x0 += k1; x1 += ks2 + 4u;
  tf_round(x0,x1,13); tf_round(x0,x1,15); tf_round(x0,x1,26); tf_round(x0,x1,6);
  x0 += ks2; x1 += k0 + 5u;
  o0 = x0; o1 = x1;
}

// ---------------- 3x3 Jacobi rotation (compile-time indices) ----------------
template<int P, int Q>
__device__ __forceinline__ void jrot(double S[3][3], double V[3][3]) {
  double apq = S[P][Q];
  if (fabs(apq) > 1e-300) {
    double tau = (S[Q][Q] - S[P][P]) / (2.0 * apq);
    double t = copysign(1.0, tau) / (fabs(tau) + sqrt(1.0 + tau * tau));
    double c = 1.0 / sqrt(1.0 + t * t);
    double sn = t * c;
    #pragma unroll
    for (int k = 0; k < 3; ++k) {
      double skp = S[k][P], skq = S[k][Q];
      S[k][P] = c * skp - sn * skq;
      S[k][Q] = sn * skp + c * skq;
    }
    #pragma unroll
    for (int k = 0; k < 3; ++k) {
      double spk = S[P][k], sqk = S[Q][k];
      S[P][k] = c * spk - sn * sqk;
      S[Q][k] = sn * spk + c * sqk;
    }
    #pragma unroll
    for (int k = 0; k < 3; ++k) {
      double vkp = V[k][P], vkq = V[k][Q];
      V[k][P] = c * vkp - sn * vkq;
      V[k][Q] = sn * vkp + c * vkq;
    }
  }
}

__device__ __forceinline__ void swapd(double& a, double& b) { double t=a; a=b; b=t; }

// ---------------- Kernel 1: model fit (one thread per (batch, iter)) ----------------
// 256 blocks x 64 threads; also zeroes `counts` (replaces a memset dispatch).
__global__ __launch_bounds__(64) void fit_kernel(
    const float* __restrict__ src, const float* __restrict__ trg,
    const float* __restrict__ wts, const float* __restrict__ Tsv,
    float* __restrict__ models /* [NBATCH][NITER][12] */,
    int* __restrict__ counts /* [NBATCH][NITER] */) {
  const int b = blockIdx.x >> 2;
  const int iter = ((blockIdx.x & 3) << 6) | threadIdx.x;

  counts[b * NITER + iter] = 0;

  // k2 = split(key(42))[1] under partitionable (fold-like) split.
  uint32_t K0, K1;
  threefry2x32(0u, 42u, 0u, 1u, K0, K1);

  const uint32_t base = (uint32_t)((iter * NBATCH + b) * NSAMP);
  int idx[NSAMP];
  #pragma unroll
  for (int s = 0; s < NSAMP; ++s) {
    uint32_t y0, y1;
    threefry2x32(K0, K1, 0u, base + (uint32_t)s, y0, y1);
    idx[s] = (int)((y0 ^ y1) & (uint32_t)(NPTS - 1));
  }

  const float* sb = src + (size_t)b * 4 * NPTS;
  const float* tb = trg + (size_t)b * 4 * NPTS;
  const float* wb = wts + (size_t)b * NPTS;

  float px[NSAMP], py[NSAMP], pz[NSAMP], qx[NSAMP], qy[NSAMP], qz[NSAMP], wv[NSAMP];
  #pragma unroll
  for (int s = 0; s < NSAMP; ++s) {
    int j = idx[s];
    px[s] = sb[j]; py[s] = sb[NPTS + j]; pz[s] = sb[2 * NPTS + j];
    qx[s] = tb[j]; qy[s] = tb[NPTS + j]; qz[s] = tb[2 * NPTS + j];
    wv[s] = wb[j];
  }

  // weighted centroids (fp64)
  double wsum = 0, csx = 0, csy = 0, csz = 0, ctx = 0, cty = 0, ctz = 0;
  #pragma unroll
  for (int s = 0; s < NSAMP; ++s) {
    double w = (double)wv[s];
    wsum += w;
    csx += (double)px[s] * w; csy += (double)py[s] * w; csz += (double)pz[s] * w;
    ctx += (double)qx[s] * w; cty += (double)qy[s] * w; ctz += (double)qz[s] * w;
  }
  double iw = 1.0 / wsum;
  csx *= iw; csy *= iw; csz *= iw; ctx *= iw; cty *= iw; ctz *= iw;

  double C00=0,C01=0,C02=0,C10=0,C11=0,C12=0,C20=0,C21=0,C22=0;
  #pragma unroll
  for (int s = 0; s < NSAMP; ++s) {
    double w = (double)wv[s];
    double ax = ((double)qx[s]-ctx)*w, ay = ((double)qy[s]-cty)*w, az = ((double)qz[s]-ctz)*w;
    double bx = (double)px[s]-csx, by = (double)py[s]-csy, bz = (double)pz[s]-csz;
    C00 += ax*bx; C01 += ax*by; C02 += ax*bz;
    C10 += ay*bx; C11 += ay*by; C12 += ay*bz;
    C20 += az*bx; C21 += az*by; C22 += az*bz;
  }

  // S = C^T C, Jacobi eigendecomposition -> V, eigenvalues on diag.
  double S[3][3], V[3][3] = {{1,0,0},{0,1,0},{0,0,1}};
  S[0][0] = C00*C00 + C10*C10 + C20*C20;
  S[0][1] = C00*C01 + C10*C11 + C20*C21;
  S[0][2] = C00*C02 + C10*C12 + C20*C22;
  S[1][1] = C01*C01 + C11*C11 + C21*C21;
  S[1][2] = C01*C02 + C11*C12 + C21*C22;
  S[2][2] = C02*C02 + C12*C12 + C22*C22;
  S[1][0] = S[0][1]; S[2][0] = S[0][2]; S[2][1] = S[1][2];
  #pragma unroll 1
  for (int sweep = 0; sweep < 6; ++sweep) {
    jrot<0,1>(S, V); jrot<0,2>(S, V); jrot<1,2>(S, V);
  }

  double l0 = S[0][0], l1 = S[1][1], l2 = S[2][2];
  double v0x=V[0][0], v0y=V[1][0], v0z=V[2][0];
  double v1x=V[0][1], v1y=V[1][1], v1z=V[2][1];
  double v2x=V[0][2], v2y=V[1][2], v2z=V[2][2];
  if (l0 < l1) { swapd(l0,l1); swapd(v0x,v1x); swapd(v0y,v1y); swapd(v0z,v1z); }
  if (l1 < l2) { swapd(l1,l2); swapd(v1x,v2x); swapd(v1y,v2y); swapd(v1z,v2z); }
  if (l0 < l1) { swapd(l0,l1); swapd(v0x,v1x); swapd(v0y,v1y); swapd(v0z,v1z); }

  double u0x = C00*v0x + C01*v0y + C02*v0z;
  double u0y = C10*v0x + C11*v0y + C12*v0z;
  double u0z = C20*v0x + C21*v0y + C22*v0z;
  double n0 = sqrt(u0x*u0x + u0y*u0y + u0z*u0z);
  double r0 = (n0 > 1e-150) ? 1.0 / n0 : 0.0;
  u0x *= r0; u0y *= r0; u0z *= r0;
  double u1x = C00*v1x + C01*v1y + C02*v1z;
  double u1y = C10*v1x + C11*v1y + C12*v1z;
  double u1z = C20*v1x + C21*v1y + C22*v1z;
  double d01 = u1x*u0x + u1y*u0y + u1z*u0z;
  u1x -= d01*u0x; u1y -= d01*u0y; u1z -= d01*u0z;
  double n1 = sqrt(u1x*u1x + u1y*u1y + u1z*u1z);
  double r1 = (n1 > 1e-150) ? 1.0 / n1 : 0.0;
  u1x *= r1; u1y *= r1; u1z *= r1;
  double u2x = u0y*u1z - u0z*u1y;
  double u2y = u0z*u1x - u0x*u1z;
  double u2z = u0x*u1y - u0y*u1x;
  double detV = v0x*(v1y*v2z - v1z*v2y) - v0y*(v1x*v2z - v1z*v2x) + v0z*(v1x*v2y - v1y*v2x);
  double R00 = u0x*v0x + u1x*v1x + detV*u2x*v2x;
  double R01 = u0x*v0y + u1x*v1y + detV*u2x*v2y;
  double R02 = u0x*v0z + u1x*v1z + detV*u2x*v2z;
  double R10 = u0y*v0x + u1y*v1x + detV*u2y*v2x;
  double R11 = u0y*v0y + u1y*v1y + detV*u2y*v2y;
  double R12 = u0y*v0z + u1y*v1z + detV*u2y*v2z;
  double R20 = u0z*v0x + u1z*v1x + detV*u2z*v2x;
  double R21 = u0z*v0y + u1z*v1y + detV*u2z*v2y;
  double R22 = u0z*v0z + u1z*v1z + detV*u2z*v2z;
  double tx = ctx - (R00*csx + R01*csy + R02*csz);
  double ty = cty - (R10*csx + R11*csy + R12*csz);
  double tz = ctz - (R20*csx + R21*csy + R22*csz);

  // T_cam = T_s_v @ T_ts @ inv(T_s_v)
  double A[4][4];
  #pragma unroll
  for (int i = 0; i < 4; ++i)
    #pragma unroll
    for (int j = 0; j < 4; ++j) A[i][j] = (double)Tsv[i*4 + j];
  double Tts[4][4] = {{R00,R01,R02,tx},{R10,R11,R12,ty},{R20,R21,R22,tz},{0,0,0,1}};
  double I[4][4];
  I[0][0]=A[0][0]; I[0][1]=A[1][0]; I[0][2]=A[2][0];
  I[1][0]=A[0][1]; I[1][1]=A[1][1]; I[1][2]=A[2][1];
  I[2][0]=A[0][2]; I[2][1]=A[1][2]; I[2][2]=A[2][2];
  I[0][3] = -(I[0][0]*A[0][3] + I[0][1]*A[1][3] + I[0][2]*A[2][3]);
  I[1][3] = -(I[1][0]*A[0][3] + I[1][1]*A[1][3] + I[1][2]*A[2][3]);
  I[2][3] = -(I[2][0]*A[0][3] + I[2][1]*A[1][3] + I[2][2]*A[2][3]);
  I[3][0]=0; I[3][1]=0; I[3][2]=0; I[3][3]=1;
  double M1[4][4];
  #pragma unroll
  for (int i = 0; i < 4; ++i)
    #pragma unroll
    for (int j = 0; j < 4; ++j)
      M1[i][j] = A[i][0]*Tts[0][j] + A[i][1]*Tts[1][j] + A[i][2]*Tts[2][j] + A[i][3]*Tts[3][j];
  float* mo = models + ((size_t)b * NITER + iter) * 12;
  #pragma unroll
  for (int i = 0; i < 3; ++i)
    #pragma unroll
    for (int j = 0; j < 4; ++j)
      mo[i*4 + j] = (float)(M1[i][0]*I[0][j] + M1[i][1]*I[1][j] + M1[i][2]*I[2][j] + M1[i][3]*I[3][j]);
}

// ---------------- Kernel 2: inlier counts ----------------
// R8 counters: VALUBusy 73%, co-limited by DS pipe (~19 DS ops / 8-pt iter).
// R9: PPT=16 (amortize), model via 3x float4 LDS broadcast, paired 16-bit
// shuffle reduce (3 shuffles/iter), valid folded into target coords.
__global__ __launch_bounds__(256) void count_kernel(
    const float* __restrict__ src, const float* __restrict__ trg,
    const int* __restrict__ vs, const int* __restrict__ vt,
    const float* __restrict__ models, int* __restrict__ counts) {
  __shared__ float4 M4[IPB * 3];
  __shared__ int cl[IPB];
  const int b      = blockIdx.x >> 5;          // 32 blocks/batch = 8 isplit * 4 chunk
  const int isplit = (blockIdx.x >> 2) & (ISPLIT - 1);
  const int chunk  = blockIdx.x & (NCHUNK - 1);
  const int ibase  = isplit * IPB;

  const float4* mb4 = (const float4*)(models + ((size_t)b * NITER + ibase) * 12);
  for (int i = threadIdx.x; i < IPB * 3; i += 256) M4[i] = mb4[i];
  if (threadIdx.x < IPB) cl[threadIdx.x] = 0;
  __syncthreads();

  const float* sb = src + (size_t)b * 4 * NPTS;
  const float* tb = trg + (size_t)b * 4 * NPTS;
  const int* vsb = vs + (size_t)b * NPTS;
  const int* vtb = vt + (size_t)b * NPTS;
  const int p0 = chunk * (256 * PPT) + threadIdx.x;

  float sx[PPT], sy[PPT], sz[PPT], tx[PPT], ty[PPT], tz[PPT];
  #pragma unroll
  for (int k = 0; k < PPT; ++k) {
    int p = p0 + k * 256;
    bool vd = (vsb[p] > 0) && (vtb[p] > 0);
    sx[k] = sb[p]; sy[k] = sb[NPTS + p]; sz[k] = sb[2 * NPTS + p];
    // fold validity: invalid -> tx=3e38 => e2=inf, never an inlier
    tx[k] = vd ? tb[p] : 3.0e38f;
    ty[k] = tb[NPTS + p]; tz[k] = tb[2 * NPTS + p];
  }

  for (int it = 0; it < IPB; it += 2) {
    float4 r0 = M4[it * 3 + 0], r1 = M4[it * 3 + 1], r2 = M4[it * 3 + 2];
    int c0 = 0;
    #pragma unroll
    for (int k = 0; k < PPT; ++k) {
      float ex = fmaf(r0.x, sx[k], fmaf(r0.y, sy[k], fmaf(r0.z, sz[k], r0.w)));
      float ey = fmaf(r1.x, sx[k], fmaf(r1.y, sy[k], fmaf(r1.z, sz[k], r1.w)));
      float ez = fmaf(r2.x, sx[k], fmaf(r2.y, sy[k], fmaf(r2.z, sz[k], r2.w)));
      float dx = tx[k] - ex, dy = ty[k] - ey, dz = tz[k] - ez;
      float e2 = fmaf(dx, dx, fmaf(dy, dy, dz * dz));
      c0 += (e2 < 0.25f) ? 1 : 0;
    }
    float4 q0 = M4[it * 3 + 3], q1 = M4[it * 3 + 4], q2 = M4[it * 3 + 5];
    int c1 = 0;
    #pragma unroll
    for (int k = 0; k < PPT; ++k) {
      float ex = fmaf(q0.x, sx[k], fmaf(q0.y, sy[k], fmaf(q0.z, sz[k], q0.w)));
      float ey = fmaf(q1.x, sx[k], fmaf(q1.y, sy[k], fmaf(q1.z, sz[k], q1.w)));
      float ez = fmaf(q2.x, sx[k], fmaf(q2.y, sy[k], fmaf(q2.z, sz[k], q2.w)));
      float dx = tx[k] - ex, dy = ty[k] - ey, dz = tz[k] - ez;
      float e2 = fmaf(dx, dx, fmaf(dy, dy, dz * dz));
      c1 += (e2 < 0.25f) ? 1 : 0;
    }
    // packed 16-bit pair reduce: fields max 16*64=1024 < 65536
    unsigned s = (unsigned)c0 | ((unsigned)c1 << 16);
    s += __shfl_xor(s, 32); s += __shfl_xor(s, 16); s += __shfl_xor(s, 8);
    s += __shfl_xor(s, 4);  s += __shfl_xor(s, 2);  s += __shfl_xor(s, 1);
    const int lane = threadIdx.x & 63;
    if (lane == 0)      atomicAdd(&cl[it],     (int)(s & 0xffffu));
    else if (lane == 1) atomicAdd(&cl[it + 1], (int)(s >> 16));
  }
  __syncthreads();
  if (threadIdx.x < IPB)
    atomicAdd(&counts[(size_t)b * NITER + ibase + threadIdx.x], cl[threadIdx.x]);
}

// ---------------- Kernel 3: argmax (fused) + write winning mask ----------------
__global__ __launch_bounds__(256) void output_kernel(
    const float* __restrict__ src, const float* __restrict__ trg,
    const int* __restrict__ vs, const int* __restrict__ vt,
    const float* __restrict__ models, const int* __restrict__ counts,
    float* __restrict__ out) {
  const int tid = blockIdx.x * 256 + threadIdx.x;
  const int b = tid >> 14;
  const int p = tid & (NPTS - 1);

  // block-wide argmax over 256 iterations (strict >, first max wins)
  __shared__ int sbest[4];
  {
    int c = counts[b * NITER + threadIdx.x];
    int key = (c << 8) | (NITER - 1 - threadIdx.x);
    key = max(key, __shfl_xor(key, 32));
    key = max(key, __shfl_xor(key, 16));
    key = max(key, __shfl_xor(key, 8));
    key = max(key, __shfl_xor(key, 4));
    key = max(key, __shfl_xor(key, 2));
    key = max(key, __shfl_xor(key, 1));
    if ((threadIdx.x & 63) == 0) sbest[threadIdx.x >> 6] = key;
  }
  __syncthreads();
  const int best = max(max(sbest[0], sbest[1]), max(sbest[2], sbest[3]));
  const int it = (NITER - 1) - (best & 255);

  const float* m = models + ((size_t)b * NITER + it) * 12;
  float m00=m[0], m01=m[1], m02=m[2],  m03=m[3];
  float m10=m[4], m11=m[5], m12=m[6],  m13=m[7];
  float m20=m[8], m21=m[9], m22=m[10], m23=m[11];
  const float* sb = src + (size_t)b * 4 * NPTS;
  const float* tb = trg + (size_t)b * 4 * NPTS;
  float sxv = sb[p], syv = sb[NPTS + p], szv = sb[2 * NPTS + p];
  float txv = tb[p], tyv = tb[NPTS + p], tzv = tb[2 * NPTS + p];
  bool v = (vs[(size_t)b * NPTS + p] > 0) && (vt[(size_t)b * NPTS + p] > 0);
  float ex = fmaf(m00, sxv, fmaf(m01, syv, fmaf(m02, szv, m03)));
  float ey = fmaf(m10, sxv, fmaf(m11, syv, fmaf(m12, szv, m13)));
  float ez = fmaf(m20, sxv, fmaf(m21, syv, fmaf(m22, szv, m23)));
  float dx = txv - ex, dy = tyv - ey, dz = tzv - ez;
  float e2 = fmaf(dx, dx, fmaf(dy, dy, dz * dz));
  out[tid] = (e2 < 0.25f && v) ? 1.0f : 0.0f;
}

extern "C" void kernel_launch(void* const* d_in, const int* in_sizes, int n_in,
                              void* d_out, int out_size, void* d_ws, size_t ws_size,
                              hipStream_t stream) {
  (void)in_sizes; (void)n_in; (void)out_size; (void)ws_size;
  const float* src = (const float*)d_in[0];
  const float* trg = (const float*)d_in[1];
  // d_in[2] = keypoints_2D_trg, unused (DIM == '3D')
  const int*   vs  = (const int*)d_in[3];
  const int*   vt  = (const int*)d_in[4];
  const float* wts = (const float*)d_in[5];
  const float* Tsv = (const float*)d_in[6];
  float* out = (float*)d_out;

  char* ws = (char*)d_ws;
  float* models = (float*)ws;                                        // 64*256*12 f32 = 768 KiB
  int* counts   = (int*)(ws + (size_t)NBATCH * NITER * 12 * 4);      // 64*256 i32  = 64 KiB

  fit_kernel<<<NBATCH * 4, 64, 0, stream>>>(src, trg, wts, Tsv, models, counts);
  count_kernel<<<NBATCH * ISPLIT * NCHUNK, 256, 0, stream>>>(src, trg, vs, vt, models, counts);
  output_kernel<<<(NBATCH * NPTS) / 256, 256, 0, stream>>>(src, trg, vs, vt, models, counts, out);
}

// Round 14
// 204.405 us; speedup vs baseline: 1.0613x; 1.0613x over previous
//
#include <hip/hip_runtime.h>
#include <stdint.h>
#include <math.h>

#define NPTS   16384
#define NBATCH 64
#define NITER  256
#define NSAMP  6
#define PPT    16         // points per thread (16 consecutive)
#define NCHUNK 4          // point chunks (256 thr * PPT pts each)
#define ISPLIT 8          // iteration splits
#define IPB    (NITER / ISPLIT)   // iterations per block = 32

// ---------------- Threefry-2x32 (exact JAX semantics) ----------------
__device__ __forceinline__ uint32_t rotl32(uint32_t v, uint32_t r) {
  return (v << r) | (v >> (32u - r));
}
__device__ __forceinline__ void tf_round(uint32_t& x0, uint32_t& x1, uint32_t r) {
  x0 += x1; x1 = rotl32(x1, r); x1 ^= x0;
}
__device__ void threefry2x32(uint32_t k0, uint32_t k1, uint32_t x0, uint32_t x1,
                             uint32_t& o0, uint32_t& o1) {
  uint32_t ks2 = k0 ^ k1 ^ 0x1BD11BDAu;
  x0 += k0; x1 += k1;
  tf_round(x0,x1,13); tf_round(x0,x1,15); tf_round(x0,x1,26); tf_round(x0,x1,6);
  x0 += k1; x1 += ks2 + 1u;
  tf_round(x0,x1,17); tf_round(x0,x1,29); tf_round(x0,x1,16); tf_round(x0,x1,24);
  x0 += ks2; x1 += k0 + 2u;
  tf_round(x0,x1,13); tf_round(x0,x1,15); tf_round(x0,x1,26); tf_round(x0,x1,6);
  x0 += k0; x1 += k1 + 3u;
  tf_round(x0,x1,17); tf_round(x0,x1,29); tf_round(x0,x1,16); tf_round(x0,x1,24);
  x0 += k1; x1 += ks2 + 4u;
  tf_round(x0,x1,13); tf_round(x0,x1,15); tf_round(x0,x1,26); tf_round(x0,x1,6);
  x0 += ks2; x1 += k0 + 5u;
  o0 = x0; o1 = x1;
}

// ---------------- 3x3 Jacobi rotation (compile-time indices) ----------------
template<int P, int Q>
__device__ __forceinline__ void jrot(double S[3][3], double V[3][3]) {
  double apq = S[P][Q];
  if (fabs(apq) > 1e-300) {
    double tau = (S[Q][Q] - S[P][P]) / (2.0 * apq);
    double t = copysign(1.0, tau) / (fabs(tau) + sqrt(1.0 + tau * tau));
    double c = 1.0 / sqrt(1.0 + t * t);
    double sn = t * c;
    #pragma unroll
    for (int k = 0; k < 3; ++k) {
      double skp = S[k][P], skq = S[k][Q];
      S[k][P] = c * skp - sn * skq;
      S[k][Q] = sn * skp + c * skq;
    }
    #pragma unroll
    for (int k = 0; k < 3; ++k) {
      double spk = S[P][k], sqk = S[Q][k];
      S[P][k] = c * spk - sn * sqk;
      S[Q][k] = sn * spk + c * sqk;
    }
    #pragma unroll
    for (int k = 0; k < 3; ++k) {
      double vkp = V[k][P], vkq = V[k][Q];
      V[k][P] = c * vkp - sn * vkq;
      V[k][Q] = sn * vkp + c * vkq;
    }
  }
}

__device__ __forceinline__ void swapd(double& a, double& b) { double t=a; a=b; b=t; }

// ---------------- Kernel 1: model fit (one thread per (batch, iter)) ----------------
// 256 blocks x 64 threads; also zeroes `counts` (replaces a memset dispatch).
__global__ __launch_bounds__(64) void fit_kernel(
    const float* __restrict__ src, const float* __restrict__ trg,
    const float* __restrict__ wts, const float* __restrict__ Tsv,
    float* __restrict__ models /* [NBATCH][NITER][12] */,
    int* __restrict__ counts /* [NBATCH][NITER] */) {
  const int b = blockIdx.x >> 2;
  const int iter = ((blockIdx.x & 3) << 6) | threadIdx.x;

  counts[b * NITER + iter] = 0;

  // k2 = split(key(42))[1] under partitionable (fold-like) split.
  uint32_t K0, K1;
  threefry2x32(0u, 42u, 0u, 1u, K0, K1);

  const uint32_t base = (uint32_t)((iter * NBATCH + b) * NSAMP);
  int idx[NSAMP];
  #pragma unroll
  for (int s = 0; s < NSAMP; ++s) {
    uint32_t y0, y1;
    threefry2x32(K0, K1, 0u, base + (uint32_t)s, y0, y1);
    idx[s] = (int)((y0 ^ y1) & (uint32_t)(NPTS - 1));
  }

  const float* sb = src + (size_t)b * 4 * NPTS;
  const float* tb = trg + (size_t)b * 4 * NPTS;
  const float* wb = wts + (size_t)b * NPTS;

  float px[NSAMP], py[NSAMP], pz[NSAMP], qx[NSAMP], qy[NSAMP], qz[NSAMP], wv[NSAMP];
  #pragma unroll
  for (int s = 0; s < NSAMP; ++s) {
    int j = idx[s];
    px[s] = sb[j]; py[s] = sb[NPTS + j]; pz[s] = sb[2 * NPTS + j];
    qx[s] = tb[j]; qy[s] = tb[NPTS + j]; qz[s] = tb[2 * NPTS + j];
    wv[s] = wb[j];
  }

  // weighted centroids (fp64)
  double wsum = 0, csx = 0, csy = 0, csz = 0, ctx = 0, cty = 0, ctz = 0;
  #pragma unroll
  for (int s = 0; s < NSAMP; ++s) {
    double w = (double)wv[s];
    wsum += w;
    csx += (double)px[s] * w; csy += (double)py[s] * w; csz += (double)pz[s] * w;
    ctx += (double)qx[s] * w; cty += (double)qy[s] * w; ctz += (double)qz[s] * w;
  }
  double iw = 1.0 / wsum;
  csx *= iw; csy *= iw; csz *= iw; ctx *= iw; cty *= iw; ctz *= iw;

  double C00=0,C01=0,C02=0,C10=0,C11=0,C12=0,C20=0,C21=0,C22=0;
  #pragma unroll
  for (int s = 0; s < NSAMP; ++s) {
    double w = (double)wv[s];
    double ax = ((double)qx[s]-ctx)*w, ay = ((double)qy[s]-cty)*w, az = ((double)qz[s]-ctz)*w;
    double bx = (double)px[s]-csx, by = (double)py[s]-csy, bz = (double)pz[s]-csz;
    C00 += ax*bx; C01 += ax*by; C02 += ax*bz;
    C10 += ay*bx; C11 += ay*by; C12 += ay*bz;
    C20 += az*bx; C21 += az*by; C22 += az*bz;
  }

  // S = C^T C, Jacobi eigendecomposition -> V, eigenvalues on diag.
  double S[3][3], V[3][3] = {{1,0,0},{0,1,0},{0,0,1}};
  S[0][0] = C00*C00 + C10*C10 + C20*C20;
  S[0][1] = C00*C01 + C10*C11 + C20*C21;
  S[0][2] = C00*C02 + C10*C12 + C20*C22;
  S[1][1] = C01*C01 + C11*C11 + C21*C21;
  S[1][2] = C01*C02 + C11*C12 + C21*C22;
  S[2][2] = C02*C02 + C12*C12 + C22*C22;
  S[1][0] = S[0][1]; S[2][0] = S[0][2]; S[2][1] = S[1][2];
  #pragma unroll 1
  for (int sweep = 0; sweep < 6; ++sweep) {
    jrot<0,1>(S, V); jrot<0,2>(S, V); jrot<1,2>(S, V);
  }

  double l0 = S[0][0], l1 = S[1][1], l2 = S[2][2];
  double v0x=V[0][0], v0y=V[1][0], v0z=V[2][0];
  double v1x=V[0][1], v1y=V[1][1], v1z=V[2][1];
  double v2x=V[0][2], v2y=V[1][2], v2z=V[2][2];
  if (l0 < l1) { swapd(l0,l1); swapd(v0x,v1x); swapd(v0y,v1y); swapd(v0z,v1z); }
  if (l1 < l2) { swapd(l1,l2); swapd(v1x,v2x); swapd(v1y,v2y); swapd(v1z,v2z); }
  if (l0 < l1) { swapd(l0,l1); swapd(v0x,v1x); swapd(v0y,v1y); swapd(v0z,v1z); }

  double u0x = C00*v0x + C01*v0y + C02*v0z;
  double u0y = C10*v0x + C11*v0y + C12*v0z;
  double u0z = C20*v0x + C21*v0y + C22*v0z;
  double n0 = sqrt(u0x*u0x + u0y*u0y + u0z*u0z);
  double r0 = (n0 > 1e-150) ? 1.0 / n0 : 0.0;
  u0x *= r0; u0y *= r0; u0z *= r0;
  double u1x = C00*v1x + C01*v1y + C02*v1z;
  double u1y = C10*v1x + C11*v1y + C12*v1z;
  double u1z = C20*v1x + C21*v1y + C22*v1z;
  double d01 = u1x*u0x + u1y*u0y + u1z*u0z;
  u1x -= d01*u0x; u1y -= d01*u0y; u1z -= d01*u0z;
  double n1 = sqrt(u1x*u1x + u1y*u1y + u1z*u1z);
  double r1 = (n1 > 1e-150) ? 1.0 / n1 : 0.0;
  u1x *= r1; u1y *= r1; u1z *= r1;
  double u2x = u0y*u1z - u0z*u1y;
  double u2y = u0z*u1x - u0x*u1z;
  double u2z = u0x*u1y - u0y*u1x;
  double detV = v0x*(v1y*v2z - v1z*v2y) - v0y*(v1x*v2z - v1z*v2x) + v0z*(v1x*v2y - v1y*v2x);
  double R00 = u0x*v0x + u1x*v1x + detV*u2x*v2x;
  double R01 = u0x*v0y + u1x*v1y + detV*u2x*v2y;
  double R02 = u0x*v0z + u1x*v1z + detV*u2x*v2z;
  double R10 = u0y*v0x + u1y*v1x + detV*u2y*v2x;
  double R11 = u0y*v0y + u1y*v1y + detV*u2y*v2y;
  double R12 = u0y*v0z + u1y*v1z + detV*u2y*v2z;
  double R20 = u0z*v0x + u1z*v1x + detV*u2z*v2x;
  double R21 = u0z*v0y + u1z*v1y + detV*u2z*v2y;
  double R22 = u0z*v0z + u1z*v1z + detV*u2z*v2z;
  double tx = ctx - (R00*csx + R01*csy + R02*csz);
  double ty = cty - (R10*csx + R11*csy + R12*csz);
  double tz = ctz - (R20*csx + R21*csy + R22*csz);

  // T_cam = T_s_v @ T_ts @ inv(T_s_v)
  double A[4][4];
  #pragma unroll
  for (int i = 0; i < 4; ++i)
    #pragma unroll
    for (int j = 0; j < 4; ++j) A[i][j] = (double)Tsv[i*4 + j];
  double Tts[4][4] = {{R00,R01,R02,tx},{R10,R11,R12,ty},{R20,R21,R22,tz},{0,0,0,1}};
  double I[4][4];
  I[0][0]=A[0][0]; I[0][1]=A[1][0]; I[0][2]=A[2][0];
  I[1][0]=A[0][1]; I[1][1]=A[1][1]; I[1][2]=A[2][1];
  I[2][0]=A[0][2]; I[2][1]=A[1][2]; I[2][2]=A[2][2];
  I[0][3] = -(I[0][0]*A[0][3] + I[0][1]*A[1][3] + I[0][2]*A[2][3]);
  I[1][3] = -(I[1][0]*A[0][3] + I[1][1]*A[1][3] + I[1][2]*A[2][3]);
  I[2][3] = -(I[2][0]*A[0][3] + I[2][1]*A[1][3] + I[2][2]*A[2][3]);
  I[3][0]=0; I[3][1]=0; I[3][2]=0; I[3][3]=1;
  double M1[4][4];
  #pragma unroll
  for (int i = 0; i < 4; ++i)
    #pragma unroll
    for (int j = 0; j < 4; ++j)
      M1[i][j] = A[i][0]*Tts[0][j] + A[i][1]*Tts[1][j] + A[i][2]*Tts[2][j] + A[i][3]*Tts[3][j];
  float* mo = models + ((size_t)b * NITER + iter) * 12;
  #pragma unroll
  for (int i = 0; i < 3; ++i)
    #pragma unroll
    for (int j = 0; j < 4; ++j)
      mo[i*4 + j] = (float)(M1[i][0]*I[0][j] + M1[i][1]*I[1][j] + M1[i][2]*I[2][j] + M1[i][3]*I[3][j]);
}

// ---------------- Kernel 2: inlier counts ----------------
// R13 post-mortem: VGPR_Count=72 < 96 point-floats => compiler DEMOTED the
// point arrays and re-streams them from L1/L2 every iteration (~50 TB/s,
// L2-BW-bound; why R8/R13 VALU fixes were neutral). Fix: __launch_bounds__
// (256,3) raises VGPR cap to ~170 so points stay register-resident;
// 16 CONSECUTIVE pts/thread -> float4/int4 loads (128->40 load instrs);
// models read via wave-uniform global loads (scalar path, no LDS).
__global__ __launch_bounds__(256, 3) void count_kernel(
    const float* __restrict__ src, const float* __restrict__ trg,
    const int* __restrict__ vs, const int* __restrict__ vt,
    const float* __restrict__ models, int* __restrict__ counts) {
  const int b      = blockIdx.x >> 5;          // 32 blocks/batch = 8 isplit * 4 chunk
  const int isplit = (blockIdx.x >> 2) & (ISPLIT - 1);
  const int chunk  = blockIdx.x & (NCHUNK - 1);
  const int ibase  = isplit * IPB;

  const float* sb = src + (size_t)b * 4 * NPTS;
  const float* tb = trg + (size_t)b * 4 * NPTS;
  const int* vsb = vs + (size_t)b * NPTS;
  const int* vtb = vt + (size_t)b * NPTS;
  const int p0 = chunk * (256 * PPT) + threadIdx.x * PPT;  // 16 consecutive pts

  float sx[PPT], sy[PPT], sz[PPT], tx[PPT], ty[PPT], tz[PPT];
  #pragma unroll
  for (int q = 0; q < PPT / 4; ++q) {
    float4 a = *(const float4*)(sb + p0 + 4 * q);
    float4 c = *(const float4*)(sb + NPTS + p0 + 4 * q);
    float4 d = *(const float4*)(sb + 2 * NPTS + p0 + 4 * q);
    float4 e = *(const float4*)(tb + p0 + 4 * q);
    float4 f = *(const float4*)(tb + NPTS + p0 + 4 * q);
    float4 g = *(const float4*)(tb + 2 * NPTS + p0 + 4 * q);
    int4 va = *(const int4*)(vsb + p0 + 4 * q);
    int4 vb = *(const int4*)(vtb + p0 + 4 * q);
    sx[4*q+0]=a.x; sx[4*q+1]=a.y; sx[4*q+2]=a.z; sx[4*q+3]=a.w;
    sy[4*q+0]=c.x; sy[4*q+1]=c.y; sy[4*q+2]=c.z; sy[4*q+3]=c.w;
    sz[4*q+0]=d.x; sz[4*q+1]=d.y; sz[4*q+2]=d.z; sz[4*q+3]=d.w;
    // fold validity: invalid -> tx=3e38 => e2 huge, never an inlier
    tx[4*q+0] = (va.x>0 && vb.x>0) ? e.x : 3.0e38f;
    tx[4*q+1] = (va.y>0 && vb.y>0) ? e.y : 3.0e38f;
    tx[4*q+2] = (va.z>0 && vb.z>0) ? e.z : 3.0e38f;
    tx[4*q+3] = (va.w>0 && vb.w>0) ? e.w : 3.0e38f;
    ty[4*q+0]=f.x; ty[4*q+1]=f.y; ty[4*q+2]=f.z; ty[4*q+3]=f.w;
    tz[4*q+0]=g.x; tz[4*q+1]=g.y; tz[4*q+2]=g.z; tz[4*q+3]=g.w;
  }

  const float* mp = models + ((size_t)b * NITER + ibase) * 12;
  #pragma unroll 1
  for (int it = 0; it < IPB; it += 2) {
    const float* m = mp + it * 12;   // wave-uniform address -> scalar loads
    float m00=m[0],  m01=m[1],  m02=m[2],  m03=m[3];
    float m10=m[4],  m11=m[5],  m12=m[6],  m13=m[7];
    float m20=m[8],  m21=m[9],  m22=m[10], m23=m[11];
    float n00=m[12], n01=m[13], n02=m[14], n03=m[15];
    float n10=m[16], n11=m[17], n12=m[18], n13=m[19];
    float n20=m[20], n21=m[21], n22=m[22], n23=m[23];
    int c0 = 0, c1 = 0;
    #pragma unroll
    for (int k = 0; k < PPT; ++k) {
      float ex = fmaf(m00, sx[k], fmaf(m01, sy[k], fmaf(m02, sz[k], m03)));
      float ey = fmaf(m10, sx[k], fmaf(m11, sy[k], fmaf(m12, sz[k], m13)));
      float ez = fmaf(m20, sx[k], fmaf(m21, sy[k], fmaf(m22, sz[k], m23)));
      float dx = tx[k] - ex, dy = ty[k] - ey, dz = tz[k] - ez;
      float e2 = fmaf(dx, dx, fmaf(dy, dy, dz * dz));
      c0 += (e2 < 0.25f) ? 1 : 0;
    }
    #pragma unroll
    for (int k = 0; k < PPT; ++k) {
      float ex = fmaf(n00, sx[k], fmaf(n01, sy[k], fmaf(n02, sz[k], n03)));
      float ey = fmaf(n10, sx[k], fmaf(n11, sy[k], fmaf(n12, sz[k], n13)));
      float ez = fmaf(n20, sx[k], fmaf(n21, sy[k], fmaf(n22, sz[k], n23)));
      float dx = tx[k] - ex, dy = ty[k] - ey, dz = tz[k] - ez;
      float e2 = fmaf(dx, dx, fmaf(dy, dy, dz * dz));
      c1 += (e2 < 0.25f) ? 1 : 0;
    }
    // packed 16-bit pair reduce: fields max 16*64=1024 < 65536
    unsigned s = (unsigned)c0 | ((unsigned)c1 << 16);
    s += __shfl_xor(s, 32); s += __shfl_xor(s, 16); s += __shfl_xor(s, 8);
    s += __shfl_xor(s, 4);  s += __shfl_xor(s, 2);  s += __shfl_xor(s, 1);
    const int lane = threadIdx.x & 63;
    if (lane == 0)      atomicAdd(&counts[(size_t)b * NITER + ibase + it],     (int)(s & 0xffffu));
    else if (lane == 1) atomicAdd(&counts[(size_t)b * NITER + ibase + it + 1], (int)(s >> 16));
  }
}

// ---------------- Kernel 3: argmax (fused) + write winning mask ----------------
__global__ __launch_bounds__(256) void output_kernel(
    const float* __restrict__ src, const float* __restrict__ trg,
    const int* __restrict__ vs, const int* __restrict__ vt,
    const float* __restrict__ models, const int* __restrict__ counts,
    float* __restrict__ out) {
  const int tid = blockIdx.x * 256 + threadIdx.x;
  const int b = tid >> 14;
  const int p = tid & (NPTS - 1);

  // block-wide argmax over 256 iterations (strict >, first max wins)
  __shared__ int sbest[4];
  {
    int c = counts[b * NITER + threadIdx.x];
    int key = (c << 8) | (NITER - 1 - threadIdx.x);
    key = max(key, __shfl_xor(key, 32));
    key = max(key, __shfl_xor(key, 16));
    key = max(key, __shfl_xor(key, 8));
    key = max(key, __shfl_xor(key, 4));
    key = max(key, __shfl_xor(key, 2));
    key = max(key, __shfl_xor(key, 1));
    if ((threadIdx.x & 63) == 0) sbest[threadIdx.x >> 6] = key;
  }
  __syncthreads();
  const int best = max(max(sbest[0], sbest[1]), max(sbest[2], sbest[3]));
  const int it = (NITER - 1) - (best & 255);

  const float* m = models + ((size_t)b * NITER + it) * 12;
  float m00=m[0], m01=m[1], m02=m[2],  m03=m[3];
  float m10=m[4], m11=m[5], m12=m[6],  m13=m[7];
  float m20=m[8], m21=m[9], m22=m[10], m23=m[11];
  const float* sb = src + (size_t)b * 4 * NPTS;
  const float* tb = trg + (size_t)b * 4 * NPTS;
  float sxv = sb[p], syv = sb[NPTS + p], szv = sb[2 * NPTS + p];
  float txv = tb[p], tyv = tb[NPTS + p], tzv = tb[2 * NPTS + p];
  bool v = (vs[(size_t)b * NPTS + p] > 0) && (vt[(size_t)b * NPTS + p] > 0);
  float ex = fmaf(m00, sxv, fmaf(m01, syv, fmaf(m02, szv, m03)));
  float ey = fmaf(m10, sxv, fmaf(m11, syv, fmaf(m12, szv, m13)));
  float ez = fmaf(m20, sxv, fmaf(m21, syv, fmaf(m22, szv, m23)));
  float dx = txv - ex, dy = tyv - ey, dz = tzv - ez;
  float e2 = fmaf(dx, dx, fmaf(dy, dy, dz * dz));
  out[tid] = (e2 < 0.25f && v) ? 1.0f : 0.0f;
}

extern "C" void kernel_launch(void* const* d_in, const int* in_sizes, int n_in,
                              void* d_out, int out_size, void* d_ws, size_t ws_size,
                              hipStream_t stream) {
  (void)in_sizes; (void)n_in; (void)out_size; (void)ws_size;
  const float* src = (const float*)d_in[0];
  const float* trg = (const float*)d_in[1];
  // d_in[2] = keypoints_2D_trg, unused (DIM == '3D')
  const int*   vs  = (const int*)d_in[3];
  const int*   vt  = (const int*)d_in[4];
  const float* wts = (const float*)d_in[5];
  const float* Tsv = (const float*)d_in[6];
  float* out = (float*)d_out;

  char* ws = (char*)d_ws;
  float* models = (float*)ws;                                        // 64*256*12 f32 = 768 KiB
  int* counts   = (int*)(ws + (size_t)NBATCH * NITER * 12 * 4);      // 64*256 i32  = 64 KiB

  fit_kernel<<<NBATCH * 4, 64, 0, stream>>>(src, trg, wts, Tsv, models, counts);
  count_kernel<<<NBATCH * ISPLIT * NCHUNK, 256, 0, stream>>>(src, trg, vs, vt, models, counts);
  output_kernel<<<(NBATCH * NPTS) / 256, 256, 0, stream>>>(src, trg, vs, vt, models, counts, out);
}